// Round 13
// baseline (456.736 us; speedup 1.0000x reference)
//
#include <hip/hip_runtime.h>

typedef unsigned short ushort_t;
typedef unsigned int uint_t;
typedef float __attribute__((ext_vector_type(4))) f32x4;
typedef float __attribute__((ext_vector_type(16))) f32x16;
typedef short __attribute__((ext_vector_type(8))) short8_t;

#define T_DATA 100000
#define E_NO 2000
#define I_NO 400
#define SUB 20
#define TNO 200
#define NBASIS 19
#define HEAD 256
#define TAILPAD 384
#define SIGSTRIDE (HEAD + T_DATA + TAILPAD)   // 100640 bf16 per (signal, subunit)
#define TILE 2048
#define RPT 8
#define MROWS 128                              // rows per k1 block (4 waves x 32)
#define CLSTR 132                              // padded t-stride for k1 LDS stage
#define ASSTR 136                              // padded elem-stride for A staging (272B, 16B-aligned)

#define OFF_Z  ((size_t)T_DATA)                       // element offset of final_Z
#define OFF_F  ((size_t)T_DATA + (size_t)T_DATA*SUB)  // element offset of out_filters

__device__ __forceinline__ float b2f(ushort_t u) {
    union { uint_t i; float f; } v; v.i = ((uint_t)u) << 16; return v.f;
}
__device__ __forceinline__ ushort_t f2b(float f) {
    union { uint_t i; float f_; } v; v.f_ = f;
    uint_t b = v.i;
    uint_t r = (b + 0x7FFFu + ((b >> 16) & 1u)) >> 16;
    return (ushort_t)r;
}
// mode: 1 = bf16 buffers, 0 = f32 buffers
__device__ __forceinline__ float ldin(const void* p, size_t idx, int mode) {
    return mode ? b2f(((const ushort_t*)p)[idx]) : ((const float*)p)[idx];
}
__device__ __forceinline__ void stout(void* p, size_t idx, float val, int mode) {
    if (mode) ((ushort_t*)p)[idx] = f2b(val);
    else      ((float*)p)[idx] = val;
}
__device__ __forceinline__ float f4get(const float4& v, int i) {
    return i == 0 ? v.x : i == 1 ? v.y : i == 2 ? v.z : v.w;
}
__device__ __forceinline__ float pick12(const float4& L, const float4& M, const float4& H, int e) {
    return e < 4 ? f4get(L, e) : e < 8 ? f4get(M, e - 4) : f4get(H, e - 8);
}
// dtype probe: Tau_spk ~3.0 each. bf16: all 20 ushorts decode to [1.5,6);
// f32: only the 10 odd (high-half) ushorts do.
__device__ __forceinline__ int detect_mode(const void* tau) {
    const ushort_t* tu = (const ushort_t*)tau;
    int cnt = 0;
    #pragma unroll
    for (int i = 0; i < 20; ++i) {
        float v = b2f(tu[i]);
        if (v >= 1.5f && v < 6.0f) cnt++;
    }
    return (cnt >= 15) ? 1 : 0;
}

// One K-chunk of the A@B GEMM: stage 32 rows x SLOTS*8 elems of A into LDS with
// LINE-DENSE coalesced loads (16 lines/instr vs the gather's 64), then NK MFMA
// k-steps reading fragments back via ds_read_b128 (stride 136 elems: 16B-aligned,
// 4-way bank alias = 1.58x, negligible). Wave-private staging -> no block barrier;
// rule-#18 lgkmcnt(0)+sched_barrier fences order ds_write vs ds_read.
template<int SLOTS, int NK>
__device__ __forceinline__ void gemm_chunk(
        const ushort_t* __restrict__ srcRow0,   // Sx + rowg0*K + kbase
        int K, const ushort_t* __restrict__ Bbase,
        ushort_t* ASw, int lane, f32x16& acc) {
    #pragma unroll
    for (int t = 0; t < 32 * SLOTS; t += 64) {
        int task = t + lane;
        int row = task / SLOTS, sl = task - row * SLOTS;
        uint4 v = *(const uint4*)(srcRow0 + (size_t)row * K + sl * 8);
        *(uint4*)(ASw + row * ASSTR + sl * 8) = v;
    }
    asm volatile("s_waitcnt lgkmcnt(0)" ::: "memory");
    __builtin_amdgcn_sched_barrier(0);
    #pragma unroll
    for (int ks = 0; ks < NK; ++ks) {
        short8_t av = *(const short8_t*)(ASw + (lane & 31) * ASSTR + ks * 16 + ((lane >> 5) << 3));
        short8_t bv = *(const short8_t*)(Bbase + ks * 512 + lane * 8);
        acc = __builtin_amdgcn_mfma_f32_32x32x16_bf16(av, bv, acc, 0, 0, 0);
    }
    asm volatile("" ::: "memory");
    __builtin_amdgcn_sched_barrier(0);
}

// ---------------- kernel 0: basis/filters, maps, B-tables, pad zeroing ----------------
// Btab layout (bf16): E: [125 ksteps][64 lanes][8 j]  (64000 elems)
//                     I: [25  ksteps][64 lanes][8 j]  (12800 elems, at +64000)
// entry = B[k][n] = C_syn[n][k] (one-hot), n = lane&31 (0 for n>=20), k = kstep*16 + (lane>>5)*8 + j
__global__ __launch_bounds__(256) void k0_prep(
        const void* Csyn_e, const void* Csyn_i,
        const void* W_syn, const void* W_hist,
        const void* W_spk, const void* Delta, const void* Tau,
        float* ws_f, int* mape, int* mapi, ushort_t* Btab, ushort_t* sigs, void* dout) {
    __shared__ int smode;
    int bid = blockIdx.x, tid = threadIdx.x;
    if (tid == 0) smode = detect_mode(Tau);
    __syncthreads();
    int mode = smode;
    if (bid < 80) {                       // filter rows: bid = kidx*20 + s
        int kidx = bid / 20, s = bid % 20;
        int tau = tid;
        if (tau < TNO) {
            float val;
            if (kidx < 3) {
                float raw = 5.0f * logf((float)tau + 1.0f);
                val = 0.f;
                for (int b = 0; b < NBASIS; ++b) {
                    float phi = 1.5707963267948966f * (float)b;
                    float d = raw - phi;
                    float basis = (d >= -3.14159265358979f && d <= 3.14159265358979f)
                                  ? (0.5f * cosf(d) + 0.5f) : 0.f;
                    float w = (kidx == 0) ? ldin(W_syn, (size_t)s * NBASIS * 2 + b * 2 + 0, mode)
                            : (kidx == 1) ? ldin(W_syn, (size_t)s * NBASIS * 2 + b * 2 + 1, mode)
                                          : ldin(W_hist, (size_t)s * NBASIS + b, mode);
                    val += w * basis;
                }
            } else {
                float dl = ldin(Delta, s, mode), tu = ldin(Tau, s, mode), wk = ldin(W_spk, s, mode);
                float t = fmaxf((float)tau - dl, 0.f);
                float tt = t / (tu * tu);
                val = tt * expf(-tt) * (wk * wk);
            }
            ws_f[kidx * 4000 + s * TNO + tau] = val;
            stout(dout, OFF_F + (size_t)bid * TNO + tau, val, mode);
        }
    } else if (bid < 96) {                // map_e (f32 fallback path)
        int e = (bid - 80) * 256 + tid;
        if (e < E_NO) {
            int m = 0;
            for (int s = 0; s < SUB; ++s)
                if (ldin(Csyn_e, (size_t)s * E_NO + e, mode) != 0.f) { m = s; break; }
            mape[e] = m;
        }
    } else if (bid < 98) {                // map_i
        int e = (bid - 96) * 256 + tid;
        if (e < I_NO) {
            int m = 0;
            for (int s = 0; s < SUB; ++s)
                if (ldin(Csyn_i, (size_t)s * I_NO + e, mode) != 0.f) { m = s; break; }
            mapi[e] = m;
        }
    } else if (bid < 158) {               // zero head+tail pads: 60 regions
        int rg = bid - 98;                // 0..59 = sig*20 + s
        int sg = rg / 20, s = rg % 20;
        ushort_t* p = sigs + (size_t)sg * SUB * SIGSTRIDE + (size_t)s * SIGSTRIDE;
        for (int i = tid; i < HEAD; i += 256) p[i] = 0;
        for (int i = tid; i < TAILPAD; i += 256) p[HEAD + T_DATA + i] = 0;
    } else if (bid < 233) {               // B-table fill: 75 blocks x 1024 entries
        int idx0 = (bid - 158) * 1024 + tid * 4;
        #pragma unroll
        for (int q = 0; q < 4; ++q) {
            int idx = idx0 + q;
            ushort_t out;
            if (idx < 64000) {
                int kstep = idx >> 9;
                int lane = (idx >> 3) & 63;
                int j = idx & 7;
                int n = lane & 31;
                int k = kstep * 16 + ((lane >> 5) << 3) + j;
                float v = (n < SUB) ? ldin(Csyn_e, (size_t)n * E_NO + k, mode) : 0.f;
                out = f2b(v);
            } else {
                int i2 = idx - 64000;
                int kstep = i2 >> 9;
                int lane = (i2 >> 3) & 63;
                int j = i2 & 7;
                int n = lane & 31;
                int k = kstep * 16 + ((lane >> 5) << 3) + j;
                float v = (n < SUB) ? ldin(Csyn_i, (size_t)n * I_NO + k, mode) : 0.f;
                out = f2b(v);
            }
            Btab[idx] = out;
        }
    }
}

// ---------------- kernel 1 v11: MFMA GEMM with LDS-staged (line-dense) A ----------
__global__ __launch_bounds__(256) void k1_reduce(
        const void* __restrict__ S_e, const void* __restrict__ S_i,
        const void* __restrict__ Z,
        const int* __restrict__ mape, const int* __restrict__ mapi,
        const ushort_t* __restrict__ Btab,
        const void* __restrict__ Tau,
        ushort_t* __restrict__ sigs) {
    __shared__ float CL[60 * CLSTR];      // rows 0..19 E, 20..39 I, 40..59 Z
    __shared__ ushort_t AS[4][32 * ASSTR];
    __shared__ int smode;
    int tid = threadIdx.x;
    if (tid == 0) smode = detect_mode(Tau);
    __syncthreads();
    int mode = smode;
    int Mbase = blockIdx.x * MROWS;
    int lane = tid & 63, wave = tid >> 6;

    // ---- Z staging (common): up to 128 rows x 20 subs, contiguous slab
    {
        int nvalid = (T_DATA - Mbase) * SUB;
        if (nvalid > MROWS * SUB) nvalid = MROWS * SUB;
        for (int e = tid * 4; e + 3 < nvalid; e += 1024) {
            float z0, z1, z2, z3;
            if (mode) {
                uint2 u = *(const uint2*)((const ushort_t*)Z + (size_t)Mbase * SUB + e);
                z0 = b2f((ushort_t)(u.x & 0xFFFF)); z1 = b2f((ushort_t)(u.x >> 16));
                z2 = b2f((ushort_t)(u.y & 0xFFFF)); z3 = b2f((ushort_t)(u.y >> 16));
            } else {
                f32x4 u = *(const f32x4*)((const float*)Z + (size_t)Mbase * SUB + e);
                z0 = u[0]; z1 = u[1]; z2 = u[2]; z3 = u[3];
            }
            CL[(40 + (e + 0) % SUB) * CLSTR + (e + 0) / SUB] = z0;
            CL[(40 + (e + 1) % SUB) * CLSTR + (e + 1) / SUB] = z1;
            CL[(40 + (e + 2) % SUB) * CLSTR + (e + 2) / SUB] = z2;
            CL[(40 + (e + 3) % SUB) * CLSTR + (e + 3) / SUB] = z3;
        }
    }

    if (mode) {
        int waveRow0 = Mbase + wave * 32;
        bool wvalid = (waveRow0 < T_DATA);       // 100000 % 32 == 0: no straddle
        int rowg0 = wvalid ? waveRow0 : 0;
        const ushort_t* Se = (const ushort_t*)S_e;
        const ushort_t* Si = (const ushort_t*)S_i;
        ushort_t* ASw = &AS[wave][0];

        f32x16 accE, accI;
        #pragma unroll
        for (int r = 0; r < 16; ++r) { accE[r] = 0.f; accI[r] = 0.f; }

        // E: 2000 = 15 chunks x 128 elems + tail 80
        const ushort_t* SeR = Se + (size_t)rowg0 * E_NO;
        for (int c = 0; c < 15; ++c)
            gemm_chunk<16, 8>(SeR + c * 128, E_NO, Btab + (size_t)(c * 8) * 512, ASw, lane, accE);
        gemm_chunk<10, 5>(SeR + 1920, E_NO, Btab + (size_t)120 * 512, ASw, lane, accE);

        // I: 400 = 3 chunks x 128 + tail 16
        const ushort_t* SiR = Si + (size_t)rowg0 * I_NO;
        for (int c = 0; c < 3; ++c)
            gemm_chunk<16, 8>(SiR + c * 128, I_NO, Btab + 64000 + (size_t)(c * 8) * 512, ASw, lane, accI);
        gemm_chunk<2, 1>(SiR + 384, I_NO, Btab + 64000 + (size_t)24 * 512, ASw, lane, accI);

        // C -> LDS: col=lane&31 is the subunit, row=(r&3)+8*(r>>2)+4*(lane>>5) is t
        int s = lane & 31;
        if (wvalid && s < SUB) {
            int thi = wave * 32 + ((lane >> 5) << 2);
            #pragma unroll
            for (int r = 0; r < 16; ++r) {
                int tloc = thi + (r & 3) + ((r >> 2) << 3);
                CL[s * CLSTR + tloc] = accE[r];
                CL[(20 + s) * CLSTR + tloc] = accI[r];
            }
        }
    } else {
        // f32 fallback: zero acc rows, then simple atomic bucket-reduce
        for (int i = tid; i < 40 * CLSTR; i += 256) CL[i] = 0.f;
        __syncthreads();
        int be[8], bi8[8];
        if (tid < 250) {
            #pragma unroll
            for (int j = 0; j < 4; ++j) be[j] = mape[tid * 4 + j] * CLSTR;
            #pragma unroll
            for (int j = 0; j < 4; ++j) be[4 + j] = mape[(tid + 250) * 4 + j] * CLSTR;
        }
        if (tid < 100) {
            #pragma unroll
            for (int j = 0; j < 4; ++j) bi8[j] = (20 + mapi[tid * 4 + j]) * CLSTR;
        }
        const float* Sef = (const float*)S_e;
        const float* Sif = (const float*)S_i;
        for (int rl = 0; rl < MROWS; ++rl) {
            int row = Mbase + rl;
            if (row >= T_DATA) break;
            if (tid < 250) {
                const float* pe = Sef + (size_t)row * E_NO;
                f32x4 a = *(const f32x4*)(pe + tid * 4);
                f32x4 b = *(const f32x4*)(pe + (tid + 250) * 4);
                #pragma unroll
                for (int q = 0; q < 4; ++q) {
                    if (a[q] != 0.f) atomicAdd(&CL[be[q] + rl], a[q]);
                    if (b[q] != 0.f) atomicAdd(&CL[be[4 + q] + rl], b[q]);
                }
            }
            if (tid < 100) {
                f32x4 c = *(const f32x4*)(Sif + (size_t)row * I_NO + tid * 4);
                #pragma unroll
                for (int q = 0; q < 4; ++q)
                    if (c[q] != 0.f) atomicAdd(&CL[bi8[q] + rl], c[q]);
            }
        }
    }
    __syncthreads();

    // Phase B: 60 signal rows x 128 t, packed bf16, 4 t per uint2 store (256B runs).
    for (int idx = tid; idx < 60 * (MROWS / 4); idx += 256) {
        int sig = idx >> 5;                // / 32
        int g = idx & 31;
        int t0 = g * 4;
        if (Mbase + t0 >= T_DATA) continue;
        const float* src = &CL[sig * CLSTR + t0];
        float4 v = *(const float4*)src;
        uint2 o;
        o.x = (uint_t)f2b(v.x) | ((uint_t)f2b(v.y) << 16);
        o.y = (uint_t)f2b(v.z) | ((uint_t)f2b(v.w) << 16);
        *(uint2*)(sigs + (size_t)sig * SIGSTRIDE + HEAD + Mbase + t0) = o;
    }
}

// ---------------- kernel 2: 4x 200-tap depthwise FIR, f32 accum (r7 version) ------
__global__ __launch_bounds__(256) void k2_conv(
        const ushort_t* __restrict__ sigs, const float* __restrict__ ws_f,
        ushort_t* __restrict__ base_out, ushort_t* __restrict__ spk_out) {
    __shared__ float X[3 * 2248 + 800];
    float* XE = X;
    float* XI = X + 2248;
    float* ZZ = X + 4496;
    float* KK = X + 6744;
    int s = blockIdx.y;
    int t0 = blockIdx.x * TILE;
    int tid = threadIdx.x;

    for (int k = 0; k < 4; ++k)
        for (int j = tid; j < TNO; j += 256)
            KK[k * TNO + j] = ws_f[k * 4000 + s * TNO + j];

    {
        const ushort_t* g0 = sigs + (size_t)s * SIGSTRIDE + (HEAD - 200) + t0;
        const ushort_t* g1 = g0 + (size_t)SUB * SIGSTRIDE;
        const ushort_t* g2 = g0 + (size_t)2 * SUB * SIGSTRIDE;
        for (int v = tid; v < 281; v += 256) {
            uint4 u = *(const uint4*)(g0 + v * 8);
            float* d = XE + v * 8;
            d[0]=b2f((ushort_t)(u.x&0xFFFF)); d[1]=b2f((ushort_t)(u.x>>16));
            d[2]=b2f((ushort_t)(u.y&0xFFFF)); d[3]=b2f((ushort_t)(u.y>>16));
            d[4]=b2f((ushort_t)(u.z&0xFFFF)); d[5]=b2f((ushort_t)(u.z>>16));
            d[6]=b2f((ushort_t)(u.w&0xFFFF)); d[7]=b2f((ushort_t)(u.w>>16));
        }
        for (int v = tid; v < 281; v += 256) {
            uint4 u = *(const uint4*)(g1 + v * 8);
            float* d = XI + v * 8;
            d[0]=b2f((ushort_t)(u.x&0xFFFF)); d[1]=b2f((ushort_t)(u.x>>16));
            d[2]=b2f((ushort_t)(u.y&0xFFFF)); d[3]=b2f((ushort_t)(u.y>>16));
            d[4]=b2f((ushort_t)(u.z&0xFFFF)); d[5]=b2f((ushort_t)(u.z>>16));
            d[6]=b2f((ushort_t)(u.w&0xFFFF)); d[7]=b2f((ushort_t)(u.w>>16));
        }
        for (int v = tid; v < 281; v += 256) {
            uint4 u = *(const uint4*)(g2 + v * 8);
            float* d = ZZ + v * 8;
            d[0]=b2f((ushort_t)(u.x&0xFFFF)); d[1]=b2f((ushort_t)(u.x>>16));
            d[2]=b2f((ushort_t)(u.y&0xFFFF)); d[3]=b2f((ushort_t)(u.y>>16));
            d[4]=b2f((ushort_t)(u.z&0xFFFF)); d[5]=b2f((ushort_t)(u.z>>16));
            d[6]=b2f((ushort_t)(u.w&0xFFFF)); d[7]=b2f((ushort_t)(u.w>>16));
        }
    }
    __syncthreads();

    float acc[RPT] = {0,0,0,0,0,0,0,0};
    float spk[RPT] = {0,0,0,0,0,0,0,0};
    const float4* XE4 = (const float4*)XE;
    const float4* XI4 = (const float4*)XI;
    const float4* ZZ4 = (const float4*)ZZ;
    const float4* KE4 = (const float4*)(KK);
    const float4* KI4 = (const float4*)(KK + 200);
    const float4* KH4 = (const float4*)(KK + 400);
    const float4* KS4 = (const float4*)(KK + 600);
    int w4 = 2 * tid + 49;                 // float4 index of window base W = 8*tid+196
    float4 eL = XE4[w4], eM = XE4[w4 + 1], eH = XE4[w4 + 2];
    float4 iL = XI4[w4], iM = XI4[w4 + 1], iH = XI4[w4 + 2];
    float4 zL = ZZ4[w4], zM = ZZ4[w4 + 1], zH = ZZ4[w4 + 2];

    for (int c = 0; c < 50; ++c) {
        if (c > 0) {
            eH = eM; eM = eL; eL = XE4[w4 - c];
            iH = iM; iM = iL; iL = XI4[w4 - c];
            zH = zM; zM = zL; zL = ZZ4[w4 - c];
        }
        float4 ke = KE4[c], ki = KI4[c], kh = KH4[c], ks = KS4[c];
        #pragma unroll
        for (int u = 0; u < 4; ++u) {
            float keu = f4get(ke, u), kiu = f4get(ki, u);
            float khu = f4get(kh, u), ksu = f4get(ks, u);
            #pragma unroll
            for (int r = 0; r < RPT; ++r) {
                float xe = pick12(eL, eM, eH, 4 + r - u);
                float xi = pick12(iL, iM, iH, 4 + r - u);
                float zz = pick12(zL, zM, zH, 3 + r - u);
                acc[r] += keu * xe;
                acc[r] += kiu * xi;
                acc[r] += khu * zz;
                spk[r] += ksu * zz;
            }
        }
    }
    int tbase = t0 + RPT * tid;
    if (tbase + RPT <= T_DATA) {
        uint4 pb, pq;
        pb.x = (uint_t)f2b(acc[0]) | ((uint_t)f2b(acc[1]) << 16);
        pb.y = (uint_t)f2b(acc[2]) | ((uint_t)f2b(acc[3]) << 16);
        pb.z = (uint_t)f2b(acc[4]) | ((uint_t)f2b(acc[5]) << 16);
        pb.w = (uint_t)f2b(acc[6]) | ((uint_t)f2b(acc[7]) << 16);
        pq.x = (uint_t)f2b(spk[0]) | ((uint_t)f2b(spk[1]) << 16);
        pq.y = (uint_t)f2b(spk[2]) | ((uint_t)f2b(spk[3]) << 16);
        pq.z = (uint_t)f2b(spk[4]) | ((uint_t)f2b(spk[5]) << 16);
        pq.w = (uint_t)f2b(spk[6]) | ((uint_t)f2b(spk[7]) << 16);
        *(uint4*)(base_out + (size_t)s * T_DATA + tbase) = pb;
        *(uint4*)(spk_out + (size_t)s * T_DATA + tbase) = pq;
    } else {
        #pragma unroll
        for (int r = 0; r < RPT; ++r) {
            int t = tbase + r;
            if (t < T_DATA) {
                base_out[(size_t)s * T_DATA + t] = f2b(acc[r]);
                spk_out[(size_t)s * T_DATA + t] = f2b(spk[r]);
            }
        }
    }
}

// ---------------- kernel 3: tree gather + MLP + outputs ----------------
__global__ __launch_bounds__(256) void k3_mlp(
        const ushort_t* __restrict__ base_out, const ushort_t* __restrict__ spk_out,
        const void* __restrict__ C_den, const void* __restrict__ Theta,
        const void* __restrict__ Vo,
        const void* __restrict__ w1, const void* __restrict__ w2,
        const void* __restrict__ w3,
        const void* __restrict__ Tau,
        void* __restrict__ dout) {
    __shared__ float cd[400], th[20], W1[120], W2[36], W3[120];
    __shared__ float vo;
    __shared__ int smode;
    int tid = threadIdx.x;
    if (tid == 0) smode = detect_mode(Tau);
    __syncthreads();
    int mode = smode;
    for (int i = tid; i < 400; i += 256) cd[i] = ldin(C_den, i, mode);
    if (tid < 20) th[tid] = ldin(Theta, tid, mode);
    if (tid < 120) W1[tid] = ldin(w1, tid, mode);
    if (tid < 36) W2[tid] = ldin(w2, tid, mode);
    if (tid >= 128 && tid < 248) W3[tid - 128] = ldin(w3, tid - 128, mode);
    if (tid == 0) vo = ldin(Vo, 0, mode);
    __syncthreads();
    int t = blockIdx.x * 256 + tid;
    if (t >= T_DATA) return;
    float sv[20], bv[20];
    #pragma unroll
    for (int c = 0; c < 20; ++c) {
        sv[c] = b2f(spk_out[(size_t)c * T_DATA + t]);
        bv[c] = b2f(base_out[(size_t)c * T_DATA + t]);
    }
    stout(dout, (size_t)t, sv[0] + vo, mode);
    #pragma unroll
    for (int p = 0; p < 20; ++p) {
        float ps = 0.f;
        #pragma unroll
        for (int c = 0; c < 20; ++c) ps += cd[p * 20 + c] * sv[c];
        float x = bv[p] + th[p] + ps;
        float h0 = x >= 0.f ? x : 0.01f * x;
        float h1[6];
        #pragma unroll
        for (int k = 0; k < 6; ++k) {
            float y = h0 * W1[p * 6 + k];
            h1[k] = y >= 0.f ? y : 0.01f * y;
        }
        float zacc = 0.f;
        #pragma unroll
        for (int j = 0; j < 6; ++j) {
            float a = 0.f;
            #pragma unroll
            for (int k = 0; k < 6; ++k) a += h1[k] * W2[k * 6 + j];
            float h2 = a >= 0.f ? a : 0.01f * a;
            zacc += h2 * W3[j * 20 + p];
        }
        float zv = 1.f / (1.f + expf(-zacc));
        stout(dout, OFF_Z + (size_t)t * SUB + p, zv, mode);
    }
}

extern "C" void kernel_launch(void* const* d_in, const int* in_sizes, int n_in,
                              void* d_out, int out_size, void* d_ws, size_t ws_size,
                              hipStream_t stream) {
    const void* S_e     = d_in[0];
    const void* S_i     = d_in[1];
    const void* Z       = d_in[2];
    const void* C_den   = d_in[3];
    const void* C_syn_e = d_in[4];
    const void* C_syn_i = d_in[5];
    const void* W_syn   = d_in[6];
    const void* W_hist  = d_in[7];
    const void* W_spk   = d_in[8];
    const void* Delta   = d_in[9];
    const void* Tau     = d_in[10];
    const void* Vo      = d_in[11];
    const void* Theta   = d_in[12];
    const void* w1      = d_in[13];
    const void* w2      = d_in[14];
    const void* w3      = d_in[15];

    char* w = (char*)d_ws;
    float*    ws_f     = (float*)(w + 64);              // 16000 f32 filters
    int*      mape     = (int*)(w + 64064);             // 2000 int
    int*      mapi     = (int*)(w + 72064);             // 400 int
    ushort_t* Btab     = (ushort_t*)(w + 73664);        // 76800 bf16 fragment table
    ushort_t* sigs     = (ushort_t*)(w + 227264);       // 60 * SIGSTRIDE bf16 = 12,076,800 B
    ushort_t* base_out = (ushort_t*)(w + 12304064);     // [20][T] bf16
    ushort_t* spk_out  = (ushort_t*)(w + 16304064);     // [20][T] bf16 (end 20,304,064 B)

    hipLaunchKernelGGL(k0_prep, dim3(233), dim3(256), 0, stream,
                       C_syn_e, C_syn_i, W_syn, W_hist, W_spk, Delta, Tau,
                       ws_f, mape, mapi, Btab, sigs, d_out);
    hipLaunchKernelGGL(k1_reduce, dim3((T_DATA + MROWS - 1) / MROWS), dim3(256), 0, stream,
                       S_e, S_i, Z, mape, mapi, Btab, Tau, sigs);
    hipLaunchKernelGGL(k2_conv, dim3((T_DATA + TILE - 1) / TILE, SUB), dim3(256), 0, stream,
                       sigs, ws_f, base_out, spk_out);
    hipLaunchKernelGGL(k3_mlp, dim3((T_DATA + 255) / 256), dim3(256), 0, stream,
                       base_out, spk_out, C_den, Theta, Vo, w1, w2, w3, Tau, d_out);
}

// Round 14
// 290.030 us; speedup vs baseline: 1.5748x; 1.5748x over previous
//
#include <hip/hip_runtime.h>

typedef unsigned short ushort_t;
typedef unsigned int uint_t;
typedef float __attribute__((ext_vector_type(4))) f32x4;

#define T_DATA 100000
#define E_NO 2000
#define I_NO 400
#define SUB 20
#define TNO 200
#define NBASIS 19
#define HEAD 256
#define TAILPAD 2048
#define SIGSTRIDE (HEAD + T_DATA + TAILPAD)   // 102304 bf16 per (signal, subunit)
#define TILE 2048
#define RPT 8
#define TSPAN 32                               // rows per k1 block (100000 = 3125*32)
#define ACCSTR 36                              // padded t-stride for k1 LDS acc

#define OFF_Z  ((size_t)T_DATA)                       // element offset of final_Z
#define OFF_F  ((size_t)T_DATA + (size_t)T_DATA*SUB)  // element offset of out_filters

__device__ __forceinline__ float b2f(ushort_t u) {
    union { uint_t i; float f; } v; v.i = ((uint_t)u) << 16; return v.f;
}
__device__ __forceinline__ ushort_t f2b(float f) {
    union { uint_t i; float f_; } v; v.f_ = f;
    uint_t b = v.i;
    uint_t r = (b + 0x7FFFu + ((b >> 16) & 1u)) >> 16;
    return (ushort_t)r;
}
// mode: 1 = bf16 buffers, 0 = f32 buffers
__device__ __forceinline__ float ldin(const void* p, size_t idx, int mode) {
    return mode ? b2f(((const ushort_t*)p)[idx]) : ((const float*)p)[idx];
}
__device__ __forceinline__ void stout(void* p, size_t idx, float val, int mode) {
    if (mode) ((ushort_t*)p)[idx] = f2b(val);
    else      ((float*)p)[idx] = val;
}
__device__ __forceinline__ float f4get(const float4& v, int i) {
    return i == 0 ? v.x : i == 1 ? v.y : i == 2 ? v.z : v.w;
}
__device__ __forceinline__ float pick12(const float4& L, const float4& M, const float4& H, int e) {
    return e < 4 ? f4get(L, e) : e < 8 ? f4get(M, e - 4) : f4get(H, e - 8);
}
// dtype probe: Tau_spk ~3.0 each. bf16: all 20 ushorts decode to [1.5,6);
// f32: only the 10 odd (high-half) ushorts do.
__device__ __forceinline__ int detect_mode(const void* tau) {
    const ushort_t* tu = (const ushort_t*)tau;
    int cnt = 0;
    #pragma unroll
    for (int i = 0; i < 20; ++i) {
        float v = b2f(tu[i]);
        if (v >= 1.5f && v < 6.0f) cnt++;
    }
    return (cnt >= 15) ? 1 : 0;
}

// ---------------- kernel 0: basis/filters, maps, pad zeroing ----------------
__global__ __launch_bounds__(256) void k0_prep(
        const void* Csyn_e, const void* Csyn_i,
        const void* W_syn, const void* W_hist,
        const void* W_spk, const void* Delta, const void* Tau,
        float* ws_f, int* mape, int* mapi, ushort_t* sigs, void* dout) {
    __shared__ int smode;
    int bid = blockIdx.x, tid = threadIdx.x;
    if (tid == 0) smode = detect_mode(Tau);
    __syncthreads();
    int mode = smode;
    if (bid < 80) {                       // filter rows: bid = kidx*20 + s
        int kidx = bid / 20, s = bid % 20;
        int tau = tid;
        if (tau < TNO) {
            float val;
            if (kidx < 3) {
                float raw = 5.0f * logf((float)tau + 1.0f);
                val = 0.f;
                for (int b = 0; b < NBASIS; ++b) {
                    float phi = 1.5707963267948966f * (float)b;
                    float d = raw - phi;
                    float basis = (d >= -3.14159265358979f && d <= 3.14159265358979f)
                                  ? (0.5f * cosf(d) + 0.5f) : 0.f;
                    float w = (kidx == 0) ? ldin(W_syn, (size_t)s * NBASIS * 2 + b * 2 + 0, mode)
                            : (kidx == 1) ? ldin(W_syn, (size_t)s * NBASIS * 2 + b * 2 + 1, mode)
                                          : ldin(W_hist, (size_t)s * NBASIS + b, mode);
                    val += w * basis;
                }
            } else {
                float dl = ldin(Delta, s, mode), tu = ldin(Tau, s, mode), wk = ldin(W_spk, s, mode);
                float t = fmaxf((float)tau - dl, 0.f);
                float tt = t / (tu * tu);
                val = tt * expf(-tt) * (wk * wk);
            }
            ws_f[kidx * 4000 + s * TNO + tau] = val;
            stout(dout, OFF_F + (size_t)bid * TNO + tau, val, mode);
        }
    } else if (bid < 96) {                // map_e
        int e = (bid - 80) * 256 + tid;
        if (e < E_NO) {
            int m = 0;
            for (int s = 0; s < SUB; ++s)
                if (ldin(Csyn_e, (size_t)s * E_NO + e, mode) != 0.f) { m = s; break; }
            mape[e] = m;
        }
    } else if (bid < 98) {                // map_i
        int e = (bid - 96) * 256 + tid;
        if (e < I_NO) {
            int m = 0;
            for (int s = 0; s < SUB; ++s)
                if (ldin(Csyn_i, (size_t)s * I_NO + e, mode) != 0.f) { m = s; break; }
            mapi[e] = m;
        }
    } else if (bid < 158) {               // zero head+tail pads: 60 regions
        int rg = bid - 98;                // 0..59 = sig*20 + s
        int sg = rg / 20, s = rg % 20;
        ushort_t* p = sigs + (size_t)sg * SUB * SIGSTRIDE + (size_t)s * SIGSTRIDE;
        for (int i = tid; i < HEAD; i += 256) p[i] = 0;
        for (int i = tid; i < TAILPAD; i += 256) p[HEAD + T_DATA + i] = 0;
    }
}

// ---------------- kernel 1 v12: wave-BALANCED 320-thread blocks ----------------
// 5 waves = 250 (S_e) + 50 (S_i, tid 250-299) + 20 (Z, tid 300-319): per-wave
// load units w0-w2: 64, w3: 58+6, w4: 44+20 (max/mean 1.1 vs 2.0 before, where
// wave 0 carried S_e AND all of S_i and stalled the block at the final barrier).
// Inner decode identical to the r7-best 4-row batch with per-element guards.
__global__ __launch_bounds__(320) void k1_reduce(
        const void* __restrict__ S_e, const void* __restrict__ S_i,
        const void* __restrict__ Z,
        const int* __restrict__ mape, const int* __restrict__ mapi,
        const void* __restrict__ Tau,
        ushort_t* __restrict__ sigs) {
    __shared__ float acc[60 * ACCSTR];
    __shared__ int smode;
    int tid = threadIdx.x;
    if (tid == 0) smode = detect_mode(Tau);
    for (int i = tid; i < 60 * ACCSTR; i += 320) acc[i] = 0.f;
    __syncthreads();
    int mode = smode;
    int base = blockIdx.x * TSPAN;

    bool le = (tid < 250);
    bool li = (tid >= 250 && tid < 300);
    bool lz = (tid >= 300);
    int si = tid - 250;                    // S_i local index (valid when li)
    int sz = tid - 300;                    // Z local index (valid when lz)

    // hoist bucket indices to registers (loop-invariant per thread)
    int be[8], bi8[8];
    if (mode) {
        if (le) {
            #pragma unroll
            for (int j = 0; j < 8; ++j) be[j] = mape[tid * 8 + j] * ACCSTR;
        }
        if (li) {
            #pragma unroll
            for (int j = 0; j < 8; ++j) bi8[j] = (20 + mapi[si * 8 + j]) * ACCSTR;
        }
    } else {
        if (le) {
            #pragma unroll
            for (int j = 0; j < 4; ++j) be[j] = mape[tid * 4 + j] * ACCSTR;
            #pragma unroll
            for (int j = 0; j < 4; ++j) be[4 + j] = mape[(tid + 250) * 4 + j] * ACCSTR;
        }
        if (li) {
            #pragma unroll
            for (int j = 0; j < 8; ++j) bi8[j] = (20 + mapi[si * 8 + j]) * ACCSTR;
        }
    }

    if (mode) {
        const ushort_t* Se = (const ushort_t*)S_e;
        const ushort_t* Si = (const ushort_t*)S_i;
        const ushort_t* Zb = (const ushort_t*)Z;
        for (int r0 = 0; r0 < TSPAN; r0 += 4) {
            uint4 u[4];
            uint4 w[4];
            float zv[4];
            if (le) {
                #pragma unroll
                for (int k = 0; k < 4; ++k)
                    u[k] = *(const uint4*)(Se + (size_t)(base + r0 + k) * E_NO + tid * 8);
            }
            if (li) {
                #pragma unroll
                for (int k = 0; k < 4; ++k)
                    w[k] = *(const uint4*)(Si + (size_t)(base + r0 + k) * I_NO + si * 8);
            }
            if (lz) {
                #pragma unroll
                for (int k = 0; k < 4; ++k)
                    zv[k] = b2f(Zb[(size_t)(base + r0 + k) * SUB + sz]);
            }
            if (le) {
                #pragma unroll
                for (int k = 0; k < 4; ++k) {
                    int rl = r0 + k;
                    uint_t wd[4] = {u[k].x, u[k].y, u[k].z, u[k].w};
                    #pragma unroll
                    for (int q = 0; q < 4; ++q) {
                        float a = b2f((ushort_t)(wd[q] & 0xFFFF));
                        float b = b2f((ushort_t)(wd[q] >> 16));
                        if (a != 0.f) atomicAdd(&acc[be[2 * q] + rl], a);
                        if (b != 0.f) atomicAdd(&acc[be[2 * q + 1] + rl], b);
                    }
                }
            }
            if (li) {
                #pragma unroll
                for (int k = 0; k < 4; ++k) {
                    int rl = r0 + k;
                    uint_t wd[4] = {w[k].x, w[k].y, w[k].z, w[k].w};
                    #pragma unroll
                    for (int q = 0; q < 4; ++q) {
                        float a = b2f((ushort_t)(wd[q] & 0xFFFF));
                        float b = b2f((ushort_t)(wd[q] >> 16));
                        if (a != 0.f) atomicAdd(&acc[bi8[2 * q] + rl], a);
                        if (b != 0.f) atomicAdd(&acc[bi8[2 * q + 1] + rl], b);
                    }
                }
            }
            if (lz) {
                #pragma unroll
                for (int k = 0; k < 4; ++k)
                    acc[(40 + sz) * ACCSTR + r0 + k] = zv[k];
            }
        }
    } else {
        const float* Sef = (const float*)S_e;
        const float* Sif = (const float*)S_i;
        const float* Zf  = (const float*)Z;
        for (int r0 = 0; r0 < TSPAN; r0 += 2) {
            f32x4 u[4];
            f32x4 w[4];
            float zv[2];
            if (le) {
                #pragma unroll
                for (int k = 0; k < 2; ++k) {
                    const float* pe = Sef + (size_t)(base + r0 + k) * E_NO;
                    u[2 * k]     = *(const f32x4*)(pe + tid * 4);
                    u[2 * k + 1] = *(const f32x4*)(pe + (tid + 250) * 4);
                }
            }
            if (li) {
                #pragma unroll
                for (int k = 0; k < 2; ++k) {
                    const float* pi = Sif + (size_t)(base + r0 + k) * I_NO;
                    w[2 * k]     = *(const f32x4*)(pi + si * 8);
                    w[2 * k + 1] = *(const f32x4*)(pi + si * 8 + 4);
                }
            }
            if (lz) {
                #pragma unroll
                for (int k = 0; k < 2; ++k)
                    zv[k] = Zf[(size_t)(base + r0 + k) * SUB + sz];
            }
            if (le) {
                #pragma unroll
                for (int k = 0; k < 2; ++k) {
                    int rl = r0 + k;
                    #pragma unroll
                    for (int q = 0; q < 4; ++q) {
                        float a = u[2 * k][q];
                        float b = u[2 * k + 1][q];
                        if (a != 0.f) atomicAdd(&acc[be[q] + rl], a);
                        if (b != 0.f) atomicAdd(&acc[be[4 + q] + rl], b);
                    }
                }
            }
            if (li) {
                #pragma unroll
                for (int k = 0; k < 2; ++k) {
                    int rl = r0 + k;
                    #pragma unroll
                    for (int q = 0; q < 4; ++q) {
                        float a = w[2 * k][q];
                        float b = w[2 * k + 1][q];
                        if (a != 0.f) atomicAdd(&acc[bi8[q] + rl], a);
                        if (b != 0.f) atomicAdd(&acc[bi8[4 + q] + rl], b);
                    }
                }
            }
            if (lz) {
                #pragma unroll
                for (int k = 0; k < 2; ++k)
                    acc[(40 + sz) * ACCSTR + r0 + k] = zv[k];
            }
        }
    }
    __syncthreads();

    // Phase B: 60 signal rows x 32 t, packed bf16, 4 t per uint2 store.
    for (int idx = tid; idx < 60 * (TSPAN / 4); idx += 320) {
        int sig = idx >> 3;                // / 8
        int g = idx & 7;
        int t0 = g * 4;
        const float* src = &acc[sig * ACCSTR + t0];
        float4 v = *(const float4*)src;
        uint2 o;
        o.x = (uint_t)f2b(v.x) | ((uint_t)f2b(v.y) << 16);
        o.y = (uint_t)f2b(v.z) | ((uint_t)f2b(v.w) << 16);
        *(uint2*)(sigs + (size_t)sig * SIGSTRIDE + HEAD + base + t0) = o;
    }
}

// ---------------- kernel 2: 4x 200-tap depthwise FIR, f32 accum (r7 version) ------
__global__ __launch_bounds__(256) void k2_conv(
        const ushort_t* __restrict__ sigs, const float* __restrict__ ws_f,
        ushort_t* __restrict__ base_out, ushort_t* __restrict__ spk_out) {
    __shared__ float X[3 * 2248 + 800];
    float* XE = X;
    float* XI = X + 2248;
    float* ZZ = X + 4496;
    float* KK = X + 6744;
    int s = blockIdx.y;
    int t0 = blockIdx.x * TILE;
    int tid = threadIdx.x;

    for (int k = 0; k < 4; ++k)
        for (int j = tid; j < TNO; j += 256)
            KK[k * TNO + j] = ws_f[k * 4000 + s * TNO + j];

    {
        const ushort_t* g0 = sigs + (size_t)s * SIGSTRIDE + (HEAD - 200) + t0;
        const ushort_t* g1 = g0 + (size_t)SUB * SIGSTRIDE;
        const ushort_t* g2 = g0 + (size_t)2 * SUB * SIGSTRIDE;
        for (int v = tid; v < 281; v += 256) {
            uint4 u = *(const uint4*)(g0 + v * 8);
            float* d = XE + v * 8;
            d[0]=b2f((ushort_t)(u.x&0xFFFF)); d[1]=b2f((ushort_t)(u.x>>16));
            d[2]=b2f((ushort_t)(u.y&0xFFFF)); d[3]=b2f((ushort_t)(u.y>>16));
            d[4]=b2f((ushort_t)(u.z&0xFFFF)); d[5]=b2f((ushort_t)(u.z>>16));
            d[6]=b2f((ushort_t)(u.w&0xFFFF)); d[7]=b2f((ushort_t)(u.w>>16));
        }
        for (int v = tid; v < 281; v += 256) {
            uint4 u = *(const uint4*)(g1 + v * 8);
            float* d = XI + v * 8;
            d[0]=b2f((ushort_t)(u.x&0xFFFF)); d[1]=b2f((ushort_t)(u.x>>16));
            d[2]=b2f((ushort_t)(u.y&0xFFFF)); d[3]=b2f((ushort_t)(u.y>>16));
            d[4]=b2f((ushort_t)(u.z&0xFFFF)); d[5]=b2f((ushort_t)(u.z>>16));
            d[6]=b2f((ushort_t)(u.w&0xFFFF)); d[7]=b2f((ushort_t)(u.w>>16));
        }
        for (int v = tid; v < 281; v += 256) {
            uint4 u = *(const uint4*)(g2 + v * 8);
            float* d = ZZ + v * 8;
            d[0]=b2f((ushort_t)(u.x&0xFFFF)); d[1]=b2f((ushort_t)(u.x>>16));
            d[2]=b2f((ushort_t)(u.y&0xFFFF)); d[3]=b2f((ushort_t)(u.y>>16));
            d[4]=b2f((ushort_t)(u.z&0xFFFF)); d[5]=b2f((ushort_t)(u.z>>16));
            d[6]=b2f((ushort_t)(u.w&0xFFFF)); d[7]=b2f((ushort_t)(u.w>>16));
        }
    }
    __syncthreads();

    float acc[RPT] = {0,0,0,0,0,0,0,0};
    float spk[RPT] = {0,0,0,0,0,0,0,0};
    const float4* XE4 = (const float4*)XE;
    const float4* XI4 = (const float4*)XI;
    const float4* ZZ4 = (const float4*)ZZ;
    const float4* KE4 = (const float4*)(KK);
    const float4* KI4 = (const float4*)(KK + 200);
    const float4* KH4 = (const float4*)(KK + 400);
    const float4* KS4 = (const float4*)(KK + 600);
    int w4 = 2 * tid + 49;                 // float4 index of window base W = 8*tid+196
    float4 eL = XE4[w4], eM = XE4[w4 + 1], eH = XE4[w4 + 2];
    float4 iL = XI4[w4], iM = XI4[w4 + 1], iH = XI4[w4 + 2];
    float4 zL = ZZ4[w4], zM = ZZ4[w4 + 1], zH = ZZ4[w4 + 2];

    for (int c = 0; c < 50; ++c) {
        if (c > 0) {
            eH = eM; eM = eL; eL = XE4[w4 - c];
            iH = iM; iM = iL; iL = XI4[w4 - c];
            zH = zM; zM = zL; zL = ZZ4[w4 - c];
        }
        float4 ke = KE4[c], ki = KI4[c], kh = KH4[c], ks = KS4[c];
        #pragma unroll
        for (int u = 0; u < 4; ++u) {
            float keu = f4get(ke, u), kiu = f4get(ki, u);
            float khu = f4get(kh, u), ksu = f4get(ks, u);
            #pragma unroll
            for (int r = 0; r < RPT; ++r) {
                float xe = pick12(eL, eM, eH, 4 + r - u);
                float xi = pick12(iL, iM, iH, 4 + r - u);
                float zz = pick12(zL, zM, zH, 3 + r - u);
                acc[r] += keu * xe;
                acc[r] += kiu * xi;
                acc[r] += khu * zz;
                spk[r] += ksu * zz;
            }
        }
    }
    int tbase = t0 + RPT * tid;
    if (tbase + RPT <= T_DATA) {
        uint4 pb, pq;
        pb.x = (uint_t)f2b(acc[0]) | ((uint_t)f2b(acc[1]) << 16);
        pb.y = (uint_t)f2b(acc[2]) | ((uint_t)f2b(acc[3]) << 16);
        pb.z = (uint_t)f2b(acc[4]) | ((uint_t)f2b(acc[5]) << 16);
        pb.w = (uint_t)f2b(acc[6]) | ((uint_t)f2b(acc[7]) << 16);
        pq.x = (uint_t)f2b(spk[0]) | ((uint_t)f2b(spk[1]) << 16);
        pq.y = (uint_t)f2b(spk[2]) | ((uint_t)f2b(spk[3]) << 16);
        pq.z = (uint_t)f2b(spk[4]) | ((uint_t)f2b(spk[5]) << 16);
        pq.w = (uint_t)f2b(spk[6]) | ((uint_t)f2b(spk[7]) << 16);
        *(uint4*)(base_out + (size_t)s * T_DATA + tbase) = pb;
        *(uint4*)(spk_out + (size_t)s * T_DATA + tbase) = pq;
    } else {
        #pragma unroll
        for (int r = 0; r < RPT; ++r) {
            int t = tbase + r;
            if (t < T_DATA) {
                base_out[(size_t)s * T_DATA + t] = f2b(acc[r]);
                spk_out[(size_t)s * T_DATA + t] = f2b(spk[r]);
            }
        }
    }
}

// ---------------- kernel 3: tree gather + MLP + outputs ----------------
__global__ __launch_bounds__(256) void k3_mlp(
        const ushort_t* __restrict__ base_out, const ushort_t* __restrict__ spk_out,
        const void* __restrict__ C_den, const void* __restrict__ Theta,
        const void* __restrict__ Vo,
        const void* __restrict__ w1, const void* __restrict__ w2,
        const void* __restrict__ w3,
        const void* __restrict__ Tau,
        void* __restrict__ dout) {
    __shared__ float cd[400], th[20], W1[120], W2[36], W3[120];
    __shared__ float vo;
    __shared__ int smode;
    int tid = threadIdx.x;
    if (tid == 0) smode = detect_mode(Tau);
    __syncthreads();
    int mode = smode;
    for (int i = tid; i < 400; i += 256) cd[i] = ldin(C_den, i, mode);
    if (tid < 20) th[tid] = ldin(Theta, tid, mode);
    if (tid < 120) W1[tid] = ldin(w1, tid, mode);
    if (tid < 36) W2[tid] = ldin(w2, tid, mode);
    if (tid >= 128 && tid < 248) W3[tid - 128] = ldin(w3, tid - 128, mode);
    if (tid == 0) vo = ldin(Vo, 0, mode);
    __syncthreads();
    int t = blockIdx.x * 256 + tid;
    if (t >= T_DATA) return;
    float sv[20], bv[20];
    #pragma unroll
    for (int c = 0; c < 20; ++c) {
        sv[c] = b2f(spk_out[(size_t)c * T_DATA + t]);
        bv[c] = b2f(base_out[(size_t)c * T_DATA + t]);
    }
    stout(dout, (size_t)t, sv[0] + vo, mode);
    #pragma unroll
    for (int p = 0; p < 20; ++p) {
        float ps = 0.f;
        #pragma unroll
        for (int c = 0; c < 20; ++c) ps += cd[p * 20 + c] * sv[c];
        float x = bv[p] + th[p] + ps;
        float h0 = x >= 0.f ? x : 0.01f * x;
        float h1[6];
        #pragma unroll
        for (int k = 0; k < 6; ++k) {
            float y = h0 * W1[p * 6 + k];
            h1[k] = y >= 0.f ? y : 0.01f * y;
        }
        float zacc = 0.f;
        #pragma unroll
        for (int j = 0; j < 6; ++j) {
            float a = 0.f;
            #pragma unroll
            for (int k = 0; k < 6; ++k) a += h1[k] * W2[k * 6 + j];
            float h2 = a >= 0.f ? a : 0.01f * a;
            zacc += h2 * W3[j * 20 + p];
        }
        float zv = 1.f / (1.f + expf(-zacc));
        stout(dout, OFF_Z + (size_t)t * SUB + p, zv, mode);
    }
}

extern "C" void kernel_launch(void* const* d_in, const int* in_sizes, int n_in,
                              void* d_out, int out_size, void* d_ws, size_t ws_size,
                              hipStream_t stream) {
    const void* S_e     = d_in[0];
    const void* S_i     = d_in[1];
    const void* Z       = d_in[2];
    const void* C_den   = d_in[3];
    const void* C_syn_e = d_in[4];
    const void* C_syn_i = d_in[5];
    const void* W_syn   = d_in[6];
    const void* W_hist  = d_in[7];
    const void* W_spk   = d_in[8];
    const void* Delta   = d_in[9];
    const void* Tau     = d_in[10];
    const void* Vo      = d_in[11];
    const void* Theta   = d_in[12];
    const void* w1      = d_in[13];
    const void* w2      = d_in[14];
    const void* w3      = d_in[15];

    char* w = (char*)d_ws;
    float*    ws_f     = (float*)(w + 64);              // 16000 f32 filters
    int*      mape     = (int*)(w + 64 + 64000);        // 2000 int
    int*      mapi     = (int*)(w + 64 + 64000 + 8000); // 400 int
    ushort_t* sigs     = (ushort_t*)(w + 73664);        // 60 * SIGSTRIDE bf16
    ushort_t* base_out = (ushort_t*)(w + 12350144);     // [20][T] bf16
    ushort_t* spk_out  = (ushort_t*)(w + 16350144);     // [20][T] bf16 (end 20350144 B)

    hipLaunchKernelGGL(k0_prep, dim3(158), dim3(256), 0, stream,
                       C_syn_e, C_syn_i, W_syn, W_hist, W_spk, Delta, Tau,
                       ws_f, mape, mapi, sigs, d_out);
    hipLaunchKernelGGL(k1_reduce, dim3(T_DATA / TSPAN), dim3(320), 0, stream,
                       S_e, S_i, Z, mape, mapi, Tau, sigs);
    hipLaunchKernelGGL(k2_conv, dim3((T_DATA + TILE - 1) / TILE, SUB), dim3(256), 0, stream,
                       sigs, ws_f, base_out, spk_out);
    hipLaunchKernelGGL(k3_mlp, dim3((T_DATA + 255) / 256), dim3(256), 0, stream,
                       base_out, spk_out, C_den, Theta, Vo, w1, w2, w3, Tau, d_out);
}